// Round 5
// baseline (154.028 us; speedup 1.0000x reference)
//
#include <hip/hip_runtime.h>

typedef unsigned short u16;
typedef unsigned int u32;
typedef __attribute__((ext_vector_type(8))) short bf16x8;
typedef __attribute__((ext_vector_type(4))) float f32x4;

__device__ __forceinline__ u16 f2bf(float x) {
  unsigned u = __float_as_uint(x);
  u += 0x7fffu + ((u >> 16) & 1u);   // RNE
  return (u16)(u >> 16);
}
__device__ __forceinline__ float bf2f(u16 z) {
  return __uint_as_float((u32)z << 16);
}

// ---- merged prep: blocks 0..2047 cast x fp32->bf16 (+rope table);
// ----              blocks 2048..3071 transpose+cast the 4 weights ----
__global__ __launch_bounds__(256) void prep(const float* __restrict__ x,
                                            const float* __restrict__ W0,
                                            const float* __restrict__ W1,
                                            const float* __restrict__ W2,
                                            const float* __restrict__ W3,
                                            u16* __restrict__ xb,
                                            u16* __restrict__ Wt,
                                            float2* __restrict__ rtab) {
  __shared__ alignas(16) u16 ls[64 * 72];
  int b = blockIdx.x;
  int tid = threadIdx.x;
  if (b < 2048) {
    int g = b * 256 + tid;
    int i = g * 4;
    float4 f = *(const float4*)(x + i);
    ushort4 o;
    o.x = f2bf(f.x); o.y = f2bf(f.y); o.z = f2bf(f.z); o.w = f2bf(f.w);
    *(ushort4*)(xb + i) = o;
    if (g < 2048 * 16) {
      int t = g >> 4, ii = g & 15;
      float fr = exp2f(-10.0f * (float)ii / 15.0f);
      float th = (float)t * fr;
      rtab[g] = make_float2(cosf(th), sinf(th));
    }
    return;
  }
  int bb = b - 2048;
  int z = bb >> 8;
  int rem = bb & 255;
  const float* W = (z == 0) ? W0 : (z == 1) ? W1 : (z == 2) ? W2 : W3;
  u16* o = Wt + (size_t)z * (1024u * 1024u);
  int kt = (rem >> 4) * 64, nt = (rem & 15) * 64;
  int r = tid >> 2, c0 = (tid & 3) * 16;
  const float* src = W + (size_t)(kt + r) * 1024 + nt + c0;
  u16 tmp[16];
#pragma unroll
  for (int c = 0; c < 16; c += 4) {
    float4 f = *(const float4*)(src + c);
    tmp[c + 0] = f2bf(f.x); tmp[c + 1] = f2bf(f.y);
    tmp[c + 2] = f2bf(f.z); tmp[c + 3] = f2bf(f.w);
  }
#pragma unroll
  for (int c = 0; c < 16; ++c) ls[r * 72 + c0 + c] = tmp[c];
  __syncthreads();
#pragma unroll
  for (int pass = 0; pass < 4; ++pass) {
    int n = pass * 16 + (tid >> 4);
    int kk = (tid & 15) * 4;
    ushort4 val;
    val.x = ls[(kk + 0) * 72 + n];
    val.y = ls[(kk + 1) * 72 + n];
    val.z = ls[(kk + 2) * 72 + n];
    val.w = ls[(kk + 3) * 72 + n];
    *(ushort4*)(o + (size_t)(nt + n) * 1024 + kt + kk) = val;
  }
}

#define GLD 40  // LDS stride: rows alias at +8 -> 2-way on banks (free)

// ---- fused QKV GEMM 128x128, full K=1024, epilogue norm+rope (q,k) / transpose (v) ----
__global__ __launch_bounds__(256) void gemm_qkv(const u16* __restrict__ A,
                                                const u16* __restrict__ Wt,
                                                u16* __restrict__ qb,
                                                u16* __restrict__ kb,
                                                u16* __restrict__ vt,
                                                const float* __restrict__ s_qk,
                                                const float2* __restrict__ rtab) {
  __shared__ alignas(16) u16 As[128 * GLD];
  __shared__ alignas(16) u16 Bs[128 * GLD];
  int z = blockIdx.z;
  const u16* B = Wt + (size_t)z * (1024u * 1024u);
  int tid = threadIdx.x;
  int bm = blockIdx.y * 128, bn = blockIdx.x * 128;
  int lane = tid & 63, w = tid >> 6;
  int wm = (w >> 1) * 64, wn = (w & 1) * 64;
  int m16 = lane & 15, q = lane >> 4;
  f32x4 acc[4][4] = {};
  int srow = tid >> 1, scol = (tid & 1) * 16;
  const u16* aptr = A + (size_t)(bm + srow) * 1024 + scol;
  const u16* bptr = B + (size_t)(bn + srow) * 1024 + scol;
  uint4 a0 = *(const uint4*)(aptr);
  uint4 a1 = *(const uint4*)(aptr + 8);
  uint4 b0 = *(const uint4*)(bptr);
  uint4 b1 = *(const uint4*)(bptr + 8);
  for (int k0 = 0; k0 < 1024; k0 += 32) {
    __syncthreads();
    *(uint4*)&As[srow * GLD + scol] = a0;
    *(uint4*)&As[srow * GLD + scol + 8] = a1;
    *(uint4*)&Bs[srow * GLD + scol] = b0;
    *(uint4*)&Bs[srow * GLD + scol + 8] = b1;
    uint4 na0, na1, nb0, nb1;
    if (k0 < 992) {
      na0 = *(const uint4*)(aptr + k0 + 32);
      na1 = *(const uint4*)(aptr + k0 + 40);
      nb0 = *(const uint4*)(bptr + k0 + 32);
      nb1 = *(const uint4*)(bptr + k0 + 40);
    }
    __syncthreads();
    bf16x8 af[4], bfr[4];
#pragma unroll
    for (int mt = 0; mt < 4; ++mt)
      af[mt] = *(const bf16x8*)&As[(wm + mt * 16 + m16) * GLD + q * 8];
#pragma unroll
    for (int nt = 0; nt < 4; ++nt)
      bfr[nt] = *(const bf16x8*)&Bs[(wn + nt * 16 + m16) * GLD + q * 8];
#pragma unroll
    for (int mt = 0; mt < 4; ++mt)
#pragma unroll
      for (int nt = 0; nt < 4; ++nt)
        acc[mt][nt] = __builtin_amdgcn_mfma_f32_16x16x32_bf16(af[mt], bfr[nt], acc[mt][nt], 0, 0, 0);
    if (k0 < 992) { a0 = na0; a1 = na1; b0 = nb0; b1 = nb1; }
  }
  int hh = (bn + wn) >> 6;
  if (z == 2) {
#pragma unroll
    for (int nt = 0; nt < 4; ++nt) {
      int n = bn + wn + nt * 16 + m16;
#pragma unroll
      for (int mt = 0; mt < 4; ++mt) {
        int t0 = bm + wm + mt * 16 + q * 4;
        ushort4 val;
        val.x = f2bf(acc[mt][nt][0]);
        val.y = f2bf(acc[mt][nt][1]);
        val.z = f2bf(acc[mt][nt][2]);
        val.w = f2bf(acc[mt][nt][3]);
        *(ushort4*)(vt + (size_t)n * 2048 + t0) = val;
      }
    }
  } else {
    u16* dst = z ? kb : qb;
    float se0 = s_qk[hh * 64 +  0 + m16] * 32.0f;   // sqrt(1024)=32
    float se1 = s_qk[hh * 64 + 16 + m16] * 32.0f;
    float se2 = s_qk[hh * 64 + 32 + m16] * 32.0f;
    float se3 = s_qk[hh * 64 + 48 + m16] * 32.0f;
#pragma unroll
    for (int mt = 0; mt < 4; ++mt)
#pragma unroll
      for (int r = 0; r < 4; ++r) {
        float ss = acc[mt][0][r] * acc[mt][0][r] + acc[mt][1][r] * acc[mt][1][r]
                 + acc[mt][2][r] * acc[mt][2][r] + acc[mt][3][r] * acc[mt][3][r];
        ss += __shfl_xor(ss, 1); ss += __shfl_xor(ss, 2);
        ss += __shfl_xor(ss, 4); ss += __shfl_xor(ss, 8);
        float inv = rsqrtf(ss + 1e-12f);
        int t = bm + wm + mt * 16 + q * 4 + r;
        float2 cs = rtab[t * 16 + m16];
        float x0 = acc[mt][0][r] * inv * se0;
        float x1 = acc[mt][1][r] * inv * se1;
        float x2 = acc[mt][2][r] * inv * se2;
        float x3 = acc[mt][3][r] * inv * se3;
        size_t off = (size_t)t * 1024 + hh * 64 + m16;
        dst[off]      = f2bf(x0 * cs.x + x2 * cs.y);
        dst[off + 16] = f2bf(x1);
        dst[off + 32] = f2bf(x2 * cs.x - x0 * cs.y);
        dst[off + 48] = f2bf(x3);
      }
  }
}

// ------------- MFMA flash attention, scheduler-folded, no partials ----------
// grid (16 h, 32 y); 256 thr (4 waves); qt = 31-y so heavy blocks dispatch
// first. 512 blocks / 256 CUs = 2 co-resident blocks per CU (LDS 27.6KB),
// pairing one heavy + one light block -> ~2 waves/SIMD and ~33 key-tiles per
// CU on average. No Zp/Lp partials; each block writes its yb rows directly.
// no-rescale softmax (|score*0.12| <= 0.27): single L per row, Y/L at end.
// K/V tile for jt+1 is register-prefetched during jt's compute (T14).
#define ALD 72
__global__ __launch_bounds__(256) void attn_flash(const u16* __restrict__ qb,
                                                  const u16* __restrict__ kb,
                                                  const u16* __restrict__ vt,
                                                  u16* __restrict__ yb) {
  __shared__ alignas(16) u16 Ks[64 * ALD];        // K tile [key][d]
  __shared__ alignas(16) u16 Vt[64 * ALD];        // V tile [d][key] (pre-transposed src)
  __shared__ alignas(16) u16 Ps[4 * 16 * ALD];    // per-wave P [row][key]
  int h = blockIdx.x;
  int qt = 31 - blockIdx.y;            // heavy q-tiles dispatch first
  int t0 = qt * 64;
  int tid = threadIdx.x;
  int lane = tid & 63, w = tid >> 6;
  int m16 = lane & 15, q = lane >> 4;
  int krow_s = tid >> 2, kcol_s = (tid & 3) * 16;   // staging: 4 thr/row, 2 uint4 each
  const u16* kbase = kb + (size_t)krow_s * 1024 + h * 64 + kcol_s;
  const u16* vbase = vt + (size_t)(h * 64 + krow_s) * 2048 + kcol_s;
  u16* pw = &Ps[w * 16 * ALD];
  const u16* qrow = qb + (size_t)(t0 + w * 16 + m16) * 1024 + h * 64;
  bf16x8 qa0 = *(const bf16x8*)(qrow + q * 8);
  bf16x8 qa1 = *(const bf16x8*)(qrow + 32 + q * 8);
  f32x4 Yacc[4] = {};
  float lsum[4] = {0.f, 0.f, 0.f, 0.f};
  int trow = t0 + w * 16 + q * 4;
  uint4 kv0 = *(const uint4*)kbase;
  uint4 kv1 = *(const uint4*)(kbase + 8);
  uint4 vv0 = *(const uint4*)vbase;
  uint4 vv1 = *(const uint4*)(vbase + 8);
  for (int jt = 0; jt <= qt; ++jt) {
    __syncthreads();   // prev-iter LDS reads complete
    *(uint4*)&Ks[krow_s * ALD + kcol_s] = kv0;
    *(uint4*)&Ks[krow_s * ALD + kcol_s + 8] = kv1;
    *(uint4*)&Vt[krow_s * ALD + kcol_s] = vv0;
    *(uint4*)&Vt[krow_s * ALD + kcol_s + 8] = vv1;
    uint4 kn0, kn1, vn0, vn1;
    if (jt < qt) {   // issue next-tile loads early; land during compute
      const u16* kp = kbase + (size_t)(jt + 1) * 65536;   // 64 rows * 1024
      const u16* vp = vbase + (jt + 1) * 64;
      kn0 = *(const uint4*)kp;
      kn1 = *(const uint4*)(kp + 8);
      vn0 = *(const uint4*)vp;
      vn1 = *(const uint4*)(vp + 8);
    }
    __syncthreads();
    // ---- scores: S[m][n] = sum_d Q[m][d] K[j0+n][d]
    f32x4 S[4] = {};
#pragma unroll
    for (int nt = 0; nt < 4; ++nt) {
      bf16x8 b0 = *(const bf16x8*)&Ks[(nt * 16 + m16) * ALD + q * 8];
      bf16x8 b1 = *(const bf16x8*)&Ks[(nt * 16 + m16) * ALD + 32 + q * 8];
      S[nt] = __builtin_amdgcn_mfma_f32_16x16x32_bf16(qa0, b0, S[nt], 0, 0, 0);
      S[nt] = __builtin_amdgcn_mfma_f32_16x16x32_bf16(qa1, b1, S[nt], 0, 0, 0);
    }
    // ---- exp + causal mask, row sums, P -> LDS
    bool diag = (jt == qt);
    int j0 = jt * 64;
    float tmp[4] = {0.f, 0.f, 0.f, 0.f};
#pragma unroll
    for (int nt = 0; nt < 4; ++nt) {
      int j = j0 + nt * 16 + m16;
#pragma unroll
      for (int r = 0; r < 4; ++r) {
        // exp(S*0.12) = exp2(S * 0.12*log2(e))
        float p = __builtin_amdgcn_exp2f(S[nt][r] * 0.17312340490667562f);
        if (diag && (j > trow + r)) p = 0.f;
        tmp[r] += p;
        pw[(q * 4 + r) * ALD + nt * 16 + m16] = f2bf(p);
      }
    }
#pragma unroll
    for (int r = 0; r < 4; ++r) {
      float s = tmp[r];
      s += __shfl_xor(s, 1); s += __shfl_xor(s, 2);
      s += __shfl_xor(s, 4); s += __shfl_xor(s, 8);
      lsum[r] += s;
    }
    // ---- P C-layout -> A-layout via wave-private LDS (no barrier needed)
    bf16x8 pa0 = *(const bf16x8*)&pw[m16 * ALD + q * 8];
    bf16x8 pa1 = *(const bf16x8*)&pw[m16 * ALD + 32 + q * 8];
    // ---- PV: Y[m][d] += sum_k P[m][k] V[k][d]
#pragma unroll
    for (int nt = 0; nt < 4; ++nt) {
      bf16x8 b0 = *(const bf16x8*)&Vt[(nt * 16 + m16) * ALD + q * 8];
      bf16x8 b1 = *(const bf16x8*)&Vt[(nt * 16 + m16) * ALD + 32 + q * 8];
      Yacc[nt] = __builtin_amdgcn_mfma_f32_16x16x32_bf16(pa0, b0, Yacc[nt], 0, 0, 0);
      Yacc[nt] = __builtin_amdgcn_mfma_f32_16x16x32_bf16(pa1, b1, Yacc[nt], 0, 0, 0);
    }
    if (jt < qt) { kv0 = kn0; kv1 = kn1; vv0 = vn0; vv1 = vn1; }
  }
  // ---- epilogue: yb[t][h*64+d] = Y/L, bf16
#pragma unroll
  for (int r = 0; r < 4; ++r) {
    float inv = __builtin_amdgcn_rcpf(lsum[r]);
    int t = t0 + w * 16 + q * 4 + r;
#pragma unroll
    for (int nt = 0; nt < 4; ++nt)
      yb[(size_t)t * 1024 + h * 64 + nt * 16 + m16] = f2bf(Yacc[nt][r] * inv);
  }
}

// ------- o-proj GEMM: out[2048][1024] fp32 = yb bf16 @ Wto^T, full K ------
__global__ __launch_bounds__(256) void gemm_o(const u16* __restrict__ A,
                                              const u16* __restrict__ B,
                                              float* __restrict__ C) {
  __shared__ alignas(16) u16 As[128 * GLD];
  __shared__ alignas(16) u16 Bs[64 * GLD];
  int tid = threadIdx.x;
  int bm = blockIdx.y * 128, bn = blockIdx.x * 64;
  int lane = tid & 63, w = tid >> 6;
  int wm = w * 32;
  int m16 = lane & 15, q = lane >> 4;
  f32x4 acc[2][4] = {};
  int srA = tid >> 1, scA = (tid & 1) * 16;
  int srB = tid >> 2, scB = (tid & 3) * 8;
  const u16* aptr = A + (size_t)(bm + srA) * 1024 + scA;
  const u16* bptr = B + (size_t)(bn + srB) * 1024 + scB;
  uint4 a0 = *(const uint4*)(aptr);
  uint4 a1 = *(const uint4*)(aptr + 8);
  uint4 b0 = *(const uint4*)(bptr);
  for (int k0 = 0; k0 < 1024; k0 += 32) {
    __syncthreads();
    *(uint4*)&As[srA * GLD + scA] = a0;
    *(uint4*)&As[srA * GLD + scA + 8] = a1;
    *(uint4*)&Bs[srB * GLD + scB] = b0;
    uint4 na0, na1, nb0;
    if (k0 < 992) {
      na0 = *(const uint4*)(aptr + k0 + 32);
      na1 = *(const uint4*)(aptr + k0 + 40);
      nb0 = *(const uint4*)(bptr + k0 + 32);
    }
    __syncthreads();
    bf16x8 af[2], bfr[4];
#pragma unroll
    for (int mt = 0; mt < 2; ++mt)
      af[mt] = *(const bf16x8*)&As[(wm + mt * 16 + m16) * GLD + q * 8];
#pragma unroll
    for (int nt = 0; nt < 4; ++nt)
      bfr[nt] = *(const bf16x8*)&Bs[(nt * 16 + m16) * GLD + q * 8];
#pragma unroll
    for (int mt = 0; mt < 2; ++mt)
#pragma unroll
      for (int nt = 0; nt < 4; ++nt)
        acc[mt][nt] = __builtin_amdgcn_mfma_f32_16x16x32_bf16(af[mt], bfr[nt], acc[mt][nt], 0, 0, 0);
    if (k0 < 992) { a0 = na0; a1 = na1; b0 = nb0; }
  }
#pragma unroll
  for (int mt = 0; mt < 2; ++mt)
#pragma unroll
    for (int nt = 0; nt < 4; ++nt)
#pragma unroll
      for (int r = 0; r < 4; ++r) {
        int row = bm + wm + mt * 16 + q * 4 + r;
        int col = bn + nt * 16 + m16;
        C[(size_t)row * 1024 + col] = acc[mt][nt][r];
      }
}

extern "C" void kernel_launch(void* const* d_in, const int* in_sizes, int n_in,
                              void* d_out, int out_size, void* d_ws, size_t ws_size,
                              hipStream_t stream) {
  const float* x   = (const float*)d_in[0];
  const float* Wq  = (const float*)d_in[1];
  const float* Wk  = (const float*)d_in[2];
  const float* Wv  = (const float*)d_in[3];
  const float* Wo  = (const float*)d_in[4];
  const float* sqk = (const float*)d_in[5];
  float* out = (float*)d_out;
  char* ws = (char*)d_ws;

  u16*    xb   = (u16*)ws;
  u16*    Wt   = (u16*)(ws + ((size_t)4 << 20));
  float2* rtab = (float2*)(ws + ((size_t)12 << 20));
  u16*    qb16 = (u16*)(ws + ((size_t)16 << 20));
  u16*    kb16 = (u16*)(ws + ((size_t)20 << 20));
  u16*    vt16 = (u16*)(ws + ((size_t)24 << 20));
  u16*    yb   = (u16*)(ws + ((size_t)28 << 20));
  u16*    Wto  = Wt + (size_t)3 * 1024 * 1024;

  prep<<<3072, 256, 0, stream>>>(x, Wq, Wk, Wv, Wo, xb, Wt, rtab);
  gemm_qkv<<<dim3(8, 16, 3), 256, 0, stream>>>(xb, Wt, qb16, kb16, vt16, sqk, rtab);
  attn_flash<<<dim3(16, 32), 256, 0, stream>>>(qb16, kb16, vt16, yb);
  gemm_o<<<dim3(16, 16), 256, 0, stream>>>(yb, Wto, out);
}

// Round 6
// 147.712 us; speedup vs baseline: 1.0428x; 1.0428x over previous
//
#include <hip/hip_runtime.h>

typedef unsigned short u16;
typedef unsigned int u32;
typedef __attribute__((ext_vector_type(8))) short bf16x8;
typedef __attribute__((ext_vector_type(4))) float f32x4;

__device__ __forceinline__ u16 f2bf(float x) {
  unsigned u = __float_as_uint(x);
  u += 0x7fffu + ((u >> 16) & 1u);   // RNE
  return (u16)(u >> 16);
}
__device__ __forceinline__ float bf2f(u16 z) {
  return __uint_as_float((u32)z << 16);
}
__device__ __forceinline__ u32 cvtpk(float lo, float hi) {
  u32 r;
  asm("v_cvt_pk_bf16_f32 %0, %1, %2" : "=v"(r) : "v"(lo), "v"(hi));
  return r;
}

// ---- merged prep: blocks 0..2047 cast x fp32->bf16 (+rope table);
// ----              blocks 2048..3071 transpose+cast the 4 weights ----
__global__ __launch_bounds__(256) void prep(const float* __restrict__ x,
                                            const float* __restrict__ W0,
                                            const float* __restrict__ W1,
                                            const float* __restrict__ W2,
                                            const float* __restrict__ W3,
                                            u16* __restrict__ xb,
                                            u16* __restrict__ Wt,
                                            float2* __restrict__ rtab) {
  __shared__ alignas(16) u16 ls[64 * 72];
  int b = blockIdx.x;
  int tid = threadIdx.x;
  if (b < 2048) {
    int g = b * 256 + tid;
    int i = g * 4;
    float4 f = *(const float4*)(x + i);
    ushort4 o;
    o.x = f2bf(f.x); o.y = f2bf(f.y); o.z = f2bf(f.z); o.w = f2bf(f.w);
    *(ushort4*)(xb + i) = o;
    if (g < 2048 * 16) {
      int t = g >> 4, ii = g & 15;
      float fr = exp2f(-10.0f * (float)ii / 15.0f);
      float th = (float)t * fr;
      rtab[g] = make_float2(cosf(th), sinf(th));
    }
    return;
  }
  int bb = b - 2048;
  int z = bb >> 8;
  int rem = bb & 255;
  const float* W = (z == 0) ? W0 : (z == 1) ? W1 : (z == 2) ? W2 : W3;
  u16* o = Wt + (size_t)z * (1024u * 1024u);
  int kt = (rem >> 4) * 64, nt = (rem & 15) * 64;
  int r = tid >> 2, c0 = (tid & 3) * 16;
  const float* src = W + (size_t)(kt + r) * 1024 + nt + c0;
  u16 tmp[16];
#pragma unroll
  for (int c = 0; c < 16; c += 4) {
    float4 f = *(const float4*)(src + c);
    tmp[c + 0] = f2bf(f.x); tmp[c + 1] = f2bf(f.y);
    tmp[c + 2] = f2bf(f.z); tmp[c + 3] = f2bf(f.w);
  }
#pragma unroll
  for (int c = 0; c < 16; ++c) ls[r * 72 + c0 + c] = tmp[c];
  __syncthreads();
#pragma unroll
  for (int pass = 0; pass < 4; ++pass) {
    int n = pass * 16 + (tid >> 4);
    int kk = (tid & 15) * 4;
    ushort4 val;
    val.x = ls[(kk + 0) * 72 + n];
    val.y = ls[(kk + 1) * 72 + n];
    val.z = ls[(kk + 2) * 72 + n];
    val.w = ls[(kk + 3) * 72 + n];
    *(ushort4*)(o + (size_t)(nt + n) * 1024 + kt + kk) = val;
  }
}

#define GLD 40  // LDS stride: rows alias at +8 -> 2-way on banks (free)

// ---- fused QKV GEMM 128x128, full K=1024, epilogue norm+rope (q,k) / transpose (v) ----
__global__ __launch_bounds__(256) void gemm_qkv(const u16* __restrict__ A,
                                                const u16* __restrict__ Wt,
                                                u16* __restrict__ qb,
                                                u16* __restrict__ kb,
                                                u16* __restrict__ vt,
                                                const float* __restrict__ s_qk,
                                                const float2* __restrict__ rtab) {
  __shared__ alignas(16) u16 As[128 * GLD];
  __shared__ alignas(16) u16 Bs[128 * GLD];
  int z = blockIdx.z;
  const u16* B = Wt + (size_t)z * (1024u * 1024u);
  int tid = threadIdx.x;
  int bm = blockIdx.y * 128, bn = blockIdx.x * 128;
  int lane = tid & 63, w = tid >> 6;
  int wm = (w >> 1) * 64, wn = (w & 1) * 64;
  int m16 = lane & 15, q = lane >> 4;
  f32x4 acc[4][4] = {};
  int srow = tid >> 1, scol = (tid & 1) * 16;
  const u16* aptr = A + (size_t)(bm + srow) * 1024 + scol;
  const u16* bptr = B + (size_t)(bn + srow) * 1024 + scol;
  uint4 a0 = *(const uint4*)(aptr);
  uint4 a1 = *(const uint4*)(aptr + 8);
  uint4 b0 = *(const uint4*)(bptr);
  uint4 b1 = *(const uint4*)(bptr + 8);
  for (int k0 = 0; k0 < 1024; k0 += 32) {
    __syncthreads();
    *(uint4*)&As[srow * GLD + scol] = a0;
    *(uint4*)&As[srow * GLD + scol + 8] = a1;
    *(uint4*)&Bs[srow * GLD + scol] = b0;
    *(uint4*)&Bs[srow * GLD + scol + 8] = b1;
    uint4 na0, na1, nb0, nb1;
    if (k0 < 992) {
      na0 = *(const uint4*)(aptr + k0 + 32);
      na1 = *(const uint4*)(aptr + k0 + 40);
      nb0 = *(const uint4*)(bptr + k0 + 32);
      nb1 = *(const uint4*)(bptr + k0 + 40);
    }
    __syncthreads();
    bf16x8 af[4], bfr[4];
#pragma unroll
    for (int mt = 0; mt < 4; ++mt)
      af[mt] = *(const bf16x8*)&As[(wm + mt * 16 + m16) * GLD + q * 8];
#pragma unroll
    for (int nt = 0; nt < 4; ++nt)
      bfr[nt] = *(const bf16x8*)&Bs[(wn + nt * 16 + m16) * GLD + q * 8];
#pragma unroll
    for (int mt = 0; mt < 4; ++mt)
#pragma unroll
      for (int nt = 0; nt < 4; ++nt)
        acc[mt][nt] = __builtin_amdgcn_mfma_f32_16x16x32_bf16(af[mt], bfr[nt], acc[mt][nt], 0, 0, 0);
    if (k0 < 992) { a0 = na0; a1 = na1; b0 = nb0; b1 = nb1; }
  }
  int hh = (bn + wn) >> 6;
  if (z == 2) {
#pragma unroll
    for (int nt = 0; nt < 4; ++nt) {
      int n = bn + wn + nt * 16 + m16;
#pragma unroll
      for (int mt = 0; mt < 4; ++mt) {
        int t0 = bm + wm + mt * 16 + q * 4;
        ushort4 val;
        val.x = f2bf(acc[mt][nt][0]);
        val.y = f2bf(acc[mt][nt][1]);
        val.z = f2bf(acc[mt][nt][2]);
        val.w = f2bf(acc[mt][nt][3]);
        *(ushort4*)(vt + (size_t)n * 2048 + t0) = val;
      }
    }
  } else {
    u16* dst = z ? kb : qb;
    float se0 = s_qk[hh * 64 +  0 + m16] * 32.0f;   // sqrt(1024)=32
    float se1 = s_qk[hh * 64 + 16 + m16] * 32.0f;
    float se2 = s_qk[hh * 64 + 32 + m16] * 32.0f;
    float se3 = s_qk[hh * 64 + 48 + m16] * 32.0f;
#pragma unroll
    for (int mt = 0; mt < 4; ++mt)
#pragma unroll
      for (int r = 0; r < 4; ++r) {
        float ss = acc[mt][0][r] * acc[mt][0][r] + acc[mt][1][r] * acc[mt][1][r]
                 + acc[mt][2][r] * acc[mt][2][r] + acc[mt][3][r] * acc[mt][3][r];
        ss += __shfl_xor(ss, 1); ss += __shfl_xor(ss, 2);
        ss += __shfl_xor(ss, 4); ss += __shfl_xor(ss, 8);
        float inv = rsqrtf(ss + 1e-12f);
        int t = bm + wm + mt * 16 + q * 4 + r;
        float2 cs = rtab[t * 16 + m16];
        float x0 = acc[mt][0][r] * inv * se0;
        float x1 = acc[mt][1][r] * inv * se1;
        float x2 = acc[mt][2][r] * inv * se2;
        float x3 = acc[mt][3][r] * inv * se3;
        size_t off = (size_t)t * 1024 + hh * 64 + m16;
        dst[off]      = f2bf(x0 * cs.x + x2 * cs.y);
        dst[off + 16] = f2bf(x1);
        dst[off + 32] = f2bf(x2 * cs.x - x0 * cs.y);
        dst[off + 48] = f2bf(x3);
      }
  }
}

// ------------- MFMA flash attention, swapped-QK^T in-register P ----------
// grid (16 h, 32 y); 256 thr (4 waves); qt = 31-y (heavy first, 2 blocks/CU).
// S^T = mfma(K_frag, Q_frag): lane holds P[qrow=m16][4 contiguous keys per nt]
// -> P->A-layout via 8 cvt_pk + 4 ds_write_b64 (was 16 ds_write_b16), and the
// row-sum becomes an in-register scalar add (was 16 shfl_xor/iter; cross-lane
// combine hoisted out of the loop). no-rescale softmax: single L per row.
#define ALD 72
__global__ __launch_bounds__(256) void attn_flash(const u16* __restrict__ qb,
                                                  const u16* __restrict__ kb,
                                                  const u16* __restrict__ vt,
                                                  u16* __restrict__ yb) {
  __shared__ alignas(16) u16 Ks[64 * ALD];        // K tile [key][d]
  __shared__ alignas(16) u16 Vt[64 * ALD];        // V tile [d][key] (pre-transposed src)
  __shared__ alignas(16) u16 Ps[4 * 16 * ALD];    // per-wave P^ [qrow][key]
  int h = blockIdx.x;
  int qt = 31 - blockIdx.y;            // heavy q-tiles dispatch first
  int t0 = qt * 64;
  int tid = threadIdx.x;
  int lane = tid & 63, w = tid >> 6;
  int m16 = lane & 15, q = lane >> 4;
  int krow_s = tid >> 2, kcol_s = (tid & 3) * 16;   // staging: 4 thr/row, 2 uint4 each
  const u16* kbase = kb + (size_t)krow_s * 1024 + h * 64 + kcol_s;
  const u16* vbase = vt + (size_t)(h * 64 + krow_s) * 2048 + kcol_s;
  u16* pw = &Ps[w * 16 * ALD];
  int qrow = t0 + w * 16 + m16;                     // this lane's q-row
  const u16* qr = qb + (size_t)qrow * 1024 + h * 64;
  bf16x8 qa0 = *(const bf16x8*)(qr + q * 8);
  bf16x8 qa1 = *(const bf16x8*)(qr + 32 + q * 8);
  f32x4 Yacc[4] = {};
  float lsum = 0.f;                                 // partial row-sum (this lane's keys)
  uint4 kv0 = *(const uint4*)kbase;
  uint4 kv1 = *(const uint4*)(kbase + 8);
  uint4 vv0 = *(const uint4*)vbase;
  uint4 vv1 = *(const uint4*)(vbase + 8);
  for (int jt = 0; jt <= qt; ++jt) {
    __syncthreads();   // prev-iter LDS reads complete
    *(uint4*)&Ks[krow_s * ALD + kcol_s] = kv0;
    *(uint4*)&Ks[krow_s * ALD + kcol_s + 8] = kv1;
    *(uint4*)&Vt[krow_s * ALD + kcol_s] = vv0;
    *(uint4*)&Vt[krow_s * ALD + kcol_s + 8] = vv1;
    uint4 kn0, kn1, vn0, vn1;
    if (jt < qt) {   // issue next-tile loads early; land during compute
      const u16* kp = kbase + (size_t)(jt + 1) * 65536;   // 64 rows * 1024
      const u16* vp = vbase + (jt + 1) * 64;
      kn0 = *(const uint4*)kp;
      kn1 = *(const uint4*)(kp + 8);
      vn0 = *(const uint4*)vp;
      vn1 = *(const uint4*)(vp + 8);
    }
    __syncthreads();
    // ---- S^T[nt] = K[nt-tile] . Q^T : rows = keys (q*4+r), col = qrow (m16)
    f32x4 ST[4] = {};
#pragma unroll
    for (int nt = 0; nt < 4; ++nt) {
      bf16x8 b0 = *(const bf16x8*)&Ks[(nt * 16 + m16) * ALD + q * 8];
      bf16x8 b1 = *(const bf16x8*)&Ks[(nt * 16 + m16) * ALD + 32 + q * 8];
      ST[nt] = __builtin_amdgcn_mfma_f32_16x16x32_bf16(b0, qa0, ST[nt], 0, 0, 0);
      ST[nt] = __builtin_amdgcn_mfma_f32_16x16x32_bf16(b1, qa1, ST[nt], 0, 0, 0);
    }
    // ---- exp + causal mask (keys in-register), pack bf16, P^ -> LDS
    bool diag = (jt == qt);
    int j0 = jt * 64;
#pragma unroll
    for (int nt = 0; nt < 4; ++nt) {
      int jbase = j0 + nt * 16 + q * 4;
      float p0 = __builtin_amdgcn_exp2f(ST[nt][0] * 0.17312340490667562f);
      float p1 = __builtin_amdgcn_exp2f(ST[nt][1] * 0.17312340490667562f);
      float p2 = __builtin_amdgcn_exp2f(ST[nt][2] * 0.17312340490667562f);
      float p3 = __builtin_amdgcn_exp2f(ST[nt][3] * 0.17312340490667562f);
      if (diag) {
        p0 = (jbase + 0 <= qrow) ? p0 : 0.f;
        p1 = (jbase + 1 <= qrow) ? p1 : 0.f;
        p2 = (jbase + 2 <= qrow) ? p2 : 0.f;
        p3 = (jbase + 3 <= qrow) ? p3 : 0.f;
      }
      lsum += (p0 + p1) + (p2 + p3);
      uint2 pk;
      pk.x = cvtpk(p0, p1);
      pk.y = cvtpk(p2, p3);
      *(uint2*)&pw[m16 * ALD + nt * 16 + q * 4] = pk;   // ds_write_b64
    }
    // ---- PV A-fragments: P^[m16][q*8..q*8+7] (+32)
    bf16x8 pa0 = *(const bf16x8*)&pw[m16 * ALD + q * 8];
    bf16x8 pa1 = *(const bf16x8*)&pw[m16 * ALD + 32 + q * 8];
    // ---- PV: Y[m][d] += sum_k P[m][k] V[k][d]
#pragma unroll
    for (int nt = 0; nt < 4; ++nt) {
      bf16x8 b0 = *(const bf16x8*)&Vt[(nt * 16 + m16) * ALD + q * 8];
      bf16x8 b1 = *(const bf16x8*)&Vt[(nt * 16 + m16) * ALD + 32 + q * 8];
      Yacc[nt] = __builtin_amdgcn_mfma_f32_16x16x32_bf16(pa0, b0, Yacc[nt], 0, 0, 0);
      Yacc[nt] = __builtin_amdgcn_mfma_f32_16x16x32_bf16(pa1, b1, Yacc[nt], 0, 0, 0);
    }
    if (jt < qt) { kv0 = kn0; kv1 = kn1; vv0 = vn0; vv1 = vn1; }
  }
  // ---- hoisted row-sum combine: total for row m16, then redistribute
  float tot = lsum;
  tot += __shfl_xor(tot, 16);
  tot += __shfl_xor(tot, 32);            // lane now holds rowsum[m16]
  // ---- epilogue: yb[t][h*64+d] = Y/L, bf16 (rows q*4+r, col d = nt*16+m16)
#pragma unroll
  for (int r = 0; r < 4; ++r) {
    float Ls = __shfl(tot, q * 4 + r);   // rowsum for row q*4+r (from lane q*4+r)
    float inv = __builtin_amdgcn_rcpf(Ls);
    int t = t0 + w * 16 + q * 4 + r;
#pragma unroll
    for (int nt = 0; nt < 4; ++nt)
      yb[(size_t)t * 1024 + h * 64 + nt * 16 + m16] = f2bf(Yacc[nt][r] * inv);
  }
}

// ------- o-proj GEMM: out[2048][1024] fp32 = yb bf16 @ Wto^T, full K ------
__global__ __launch_bounds__(256) void gemm_o(const u16* __restrict__ A,
                                              const u16* __restrict__ B,
                                              float* __restrict__ C) {
  __shared__ alignas(16) u16 As[128 * GLD];
  __shared__ alignas(16) u16 Bs[64 * GLD];
  int tid = threadIdx.x;
  int bm = blockIdx.y * 128, bn = blockIdx.x * 64;
  int lane = tid & 63, w = tid >> 6;
  int wm = w * 32;
  int m16 = lane & 15, q = lane >> 4;
  f32x4 acc[2][4] = {};
  int srA = tid >> 1, scA = (tid & 1) * 16;
  int srB = tid >> 2, scB = (tid & 3) * 8;
  const u16* aptr = A + (size_t)(bm + srA) * 1024 + scA;
  const u16* bptr = B + (size_t)(bn + srB) * 1024 + scB;
  uint4 a0 = *(const uint4*)(aptr);
  uint4 a1 = *(const uint4*)(aptr + 8);
  uint4 b0 = *(const uint4*)(bptr);
  for (int k0 = 0; k0 < 1024; k0 += 32) {
    __syncthreads();
    *(uint4*)&As[srA * GLD + scA] = a0;
    *(uint4*)&As[srA * GLD + scA + 8] = a1;
    *(uint4*)&Bs[srB * GLD + scB] = b0;
    uint4 na0, na1, nb0;
    if (k0 < 992) {
      na0 = *(const uint4*)(aptr + k0 + 32);
      na1 = *(const uint4*)(aptr + k0 + 40);
      nb0 = *(const uint4*)(bptr + k0 + 32);
    }
    __syncthreads();
    bf16x8 af[2], bfr[4];
#pragma unroll
    for (int mt = 0; mt < 2; ++mt)
      af[mt] = *(const bf16x8*)&As[(wm + mt * 16 + m16) * GLD + q * 8];
#pragma unroll
    for (int nt = 0; nt < 4; ++nt)
      bfr[nt] = *(const bf16x8*)&Bs[(nt * 16 + m16) * GLD + q * 8];
#pragma unroll
    for (int mt = 0; mt < 2; ++mt)
#pragma unroll
      for (int nt = 0; nt < 4; ++nt)
        acc[mt][nt] = __builtin_amdgcn_mfma_f32_16x16x32_bf16(af[mt], bfr[nt], acc[mt][nt], 0, 0, 0);
    if (k0 < 992) { a0 = na0; a1 = na1; b0 = nb0; }
  }
#pragma unroll
  for (int mt = 0; mt < 2; ++mt)
#pragma unroll
    for (int nt = 0; nt < 4; ++nt)
#pragma unroll
      for (int r = 0; r < 4; ++r) {
        int row = bm + wm + mt * 16 + q * 4 + r;
        int col = bn + nt * 16 + m16;
        C[(size_t)row * 1024 + col] = acc[mt][nt][r];
      }
}

extern "C" void kernel_launch(void* const* d_in, const int* in_sizes, int n_in,
                              void* d_out, int out_size, void* d_ws, size_t ws_size,
                              hipStream_t stream) {
  const float* x   = (const float*)d_in[0];
  const float* Wq  = (const float*)d_in[1];
  const float* Wk  = (const float*)d_in[2];
  const float* Wv  = (const float*)d_in[3];
  const float* Wo  = (const float*)d_in[4];
  const float* sqk = (const float*)d_in[5];
  float* out = (float*)d_out;
  char* ws = (char*)d_ws;

  u16*    xb   = (u16*)ws;
  u16*    Wt   = (u16*)(ws + ((size_t)4 << 20));
  float2* rtab = (float2*)(ws + ((size_t)12 << 20));
  u16*    qb16 = (u16*)(ws + ((size_t)16 << 20));
  u16*    kb16 = (u16*)(ws + ((size_t)20 << 20));
  u16*    vt16 = (u16*)(ws + ((size_t)24 << 20));
  u16*    yb   = (u16*)(ws + ((size_t)28 << 20));
  u16*    Wto  = Wt + (size_t)3 * 1024 * 1024;

  prep<<<3072, 256, 0, stream>>>(x, Wq, Wk, Wv, Wo, xb, Wt, rtab);
  gemm_qkv<<<dim3(8, 16, 3), 256, 0, stream>>>(xb, Wt, qb16, kb16, vt16, sqk, rtab);
  attn_flash<<<dim3(16, 32), 256, 0, stream>>>(qb16, kb16, vt16, yb);
  gemm_o<<<dim3(16, 16), 256, 0, stream>>>(yb, Wto, out);
}

// Round 7
// 145.592 us; speedup vs baseline: 1.0579x; 1.0146x over previous
//
#include <hip/hip_runtime.h>

typedef unsigned short u16;
typedef unsigned int u32;
typedef __attribute__((ext_vector_type(8))) short bf16x8;
typedef __attribute__((ext_vector_type(4))) float f32x4;

__device__ __forceinline__ u16 f2bf(float x) {
  unsigned u = __float_as_uint(x);
  u += 0x7fffu + ((u >> 16) & 1u);   // RNE
  return (u16)(u >> 16);
}
__device__ __forceinline__ float bf2f(u16 z) {
  return __uint_as_float((u32)z << 16);
}
__device__ __forceinline__ u32 cvtpk(float lo, float hi) {
  u32 r;
  asm("v_cvt_pk_bf16_f32 %0, %1, %2" : "=v"(r) : "v"(lo), "v"(hi));
  return r;
}

// ---- merged prep: blocks 0..2047 cast x fp32->bf16 (+rope table);
// ----              blocks 2048..3071 transpose+cast the 4 weights ----
__global__ __launch_bounds__(256) void prep(const float* __restrict__ x,
                                            const float* __restrict__ W0,
                                            const float* __restrict__ W1,
                                            const float* __restrict__ W2,
                                            const float* __restrict__ W3,
                                            u16* __restrict__ xb,
                                            u16* __restrict__ Wt,
                                            float2* __restrict__ rtab) {
  __shared__ alignas(16) u16 ls[64 * 72];
  int b = blockIdx.x;
  int tid = threadIdx.x;
  if (b < 2048) {
    int g = b * 256 + tid;
    int i = g * 4;
    float4 f = *(const float4*)(x + i);
    ushort4 o;
    o.x = f2bf(f.x); o.y = f2bf(f.y); o.z = f2bf(f.z); o.w = f2bf(f.w);
    *(ushort4*)(xb + i) = o;
    if (g < 2048 * 16) {
      int t = g >> 4, ii = g & 15;
      float fr = exp2f(-10.0f * (float)ii / 15.0f);
      float th = (float)t * fr;
      rtab[g] = make_float2(cosf(th), sinf(th));
    }
    return;
  }
  int bb = b - 2048;
  int z = bb >> 8;
  int rem = bb & 255;
  const float* W = (z == 0) ? W0 : (z == 1) ? W1 : (z == 2) ? W2 : W3;
  u16* o = Wt + (size_t)z * (1024u * 1024u);
  int kt = (rem >> 4) * 64, nt = (rem & 15) * 64;
  int r = tid >> 2, c0 = (tid & 3) * 16;
  const float* src = W + (size_t)(kt + r) * 1024 + nt + c0;
  u16 tmp[16];
#pragma unroll
  for (int c = 0; c < 16; c += 4) {
    float4 f = *(const float4*)(src + c);
    tmp[c + 0] = f2bf(f.x); tmp[c + 1] = f2bf(f.y);
    tmp[c + 2] = f2bf(f.z); tmp[c + 3] = f2bf(f.w);
  }
#pragma unroll
  for (int c = 0; c < 16; ++c) ls[r * 72 + c0 + c] = tmp[c];
  __syncthreads();
#pragma unroll
  for (int pass = 0; pass < 4; ++pass) {
    int n = pass * 16 + (tid >> 4);
    int kk = (tid & 15) * 4;
    ushort4 val;
    val.x = ls[(kk + 0) * 72 + n];
    val.y = ls[(kk + 1) * 72 + n];
    val.z = ls[(kk + 2) * 72 + n];
    val.w = ls[(kk + 3) * 72 + n];
    *(ushort4*)(o + (size_t)(nt + n) * 1024 + kt + kk) = val;
  }
}

#define GLD 40  // LDS stride: rows alias at +8 -> 2-way on banks (free)

// ---- fused QKV GEMM 128x128, full K=1024, epilogue norm+rope (q,k) / transpose (v) ----
__global__ __launch_bounds__(256) void gemm_qkv(const u16* __restrict__ A,
                                                const u16* __restrict__ Wt,
                                                u16* __restrict__ qb,
                                                u16* __restrict__ kb,
                                                u16* __restrict__ vt,
                                                const float* __restrict__ s_qk,
                                                const float2* __restrict__ rtab) {
  __shared__ alignas(16) u16 As[128 * GLD];
  __shared__ alignas(16) u16 Bs[128 * GLD];
  int z = blockIdx.z;
  const u16* B = Wt + (size_t)z * (1024u * 1024u);
  int tid = threadIdx.x;
  int bm = blockIdx.y * 128, bn = blockIdx.x * 128;
  int lane = tid & 63, w = tid >> 6;
  int wm = (w >> 1) * 64, wn = (w & 1) * 64;
  int m16 = lane & 15, q = lane >> 4;
  f32x4 acc[4][4] = {};
  int srow = tid >> 1, scol = (tid & 1) * 16;
  const u16* aptr = A + (size_t)(bm + srow) * 1024 + scol;
  const u16* bptr = B + (size_t)(bn + srow) * 1024 + scol;
  uint4 a0 = *(const uint4*)(aptr);
  uint4 a1 = *(const uint4*)(aptr + 8);
  uint4 b0 = *(const uint4*)(bptr);
  uint4 b1 = *(const uint4*)(bptr + 8);
  for (int k0 = 0; k0 < 1024; k0 += 32) {
    __syncthreads();
    *(uint4*)&As[srow * GLD + scol] = a0;
    *(uint4*)&As[srow * GLD + scol + 8] = a1;
    *(uint4*)&Bs[srow * GLD + scol] = b0;
    *(uint4*)&Bs[srow * GLD + scol + 8] = b1;
    uint4 na0, na1, nb0, nb1;
    if (k0 < 992) {
      na0 = *(const uint4*)(aptr + k0 + 32);
      na1 = *(const uint4*)(aptr + k0 + 40);
      nb0 = *(const uint4*)(bptr + k0 + 32);
      nb1 = *(const uint4*)(bptr + k0 + 40);
    }
    __syncthreads();
    bf16x8 af[4], bfr[4];
#pragma unroll
    for (int mt = 0; mt < 4; ++mt)
      af[mt] = *(const bf16x8*)&As[(wm + mt * 16 + m16) * GLD + q * 8];
#pragma unroll
    for (int nt = 0; nt < 4; ++nt)
      bfr[nt] = *(const bf16x8*)&Bs[(wn + nt * 16 + m16) * GLD + q * 8];
#pragma unroll
    for (int mt = 0; mt < 4; ++mt)
#pragma unroll
      for (int nt = 0; nt < 4; ++nt)
        acc[mt][nt] = __builtin_amdgcn_mfma_f32_16x16x32_bf16(af[mt], bfr[nt], acc[mt][nt], 0, 0, 0);
    if (k0 < 992) { a0 = na0; a1 = na1; b0 = nb0; b1 = nb1; }
  }
  int hh = (bn + wn) >> 6;
  if (z == 2) {
#pragma unroll
    for (int nt = 0; nt < 4; ++nt) {
      int n = bn + wn + nt * 16 + m16;
#pragma unroll
      for (int mt = 0; mt < 4; ++mt) {
        int t0 = bm + wm + mt * 16 + q * 4;
        ushort4 val;
        val.x = f2bf(acc[mt][nt][0]);
        val.y = f2bf(acc[mt][nt][1]);
        val.z = f2bf(acc[mt][nt][2]);
        val.w = f2bf(acc[mt][nt][3]);
        *(ushort4*)(vt + (size_t)n * 2048 + t0) = val;
      }
    }
  } else {
    u16* dst = z ? kb : qb;
    float se0 = s_qk[hh * 64 +  0 + m16] * 32.0f;   // sqrt(1024)=32
    float se1 = s_qk[hh * 64 + 16 + m16] * 32.0f;
    float se2 = s_qk[hh * 64 + 32 + m16] * 32.0f;
    float se3 = s_qk[hh * 64 + 48 + m16] * 32.0f;
#pragma unroll
    for (int mt = 0; mt < 4; ++mt)
#pragma unroll
      for (int r = 0; r < 4; ++r) {
        float ss = acc[mt][0][r] * acc[mt][0][r] + acc[mt][1][r] * acc[mt][1][r]
                 + acc[mt][2][r] * acc[mt][2][r] + acc[mt][3][r] * acc[mt][3][r];
        ss += __shfl_xor(ss, 1); ss += __shfl_xor(ss, 2);
        ss += __shfl_xor(ss, 4); ss += __shfl_xor(ss, 8);
        float inv = rsqrtf(ss + 1e-12f);
        int t = bm + wm + mt * 16 + q * 4 + r;
        float2 cs = rtab[t * 16 + m16];
        float x0 = acc[mt][0][r] * inv * se0;
        float x1 = acc[mt][1][r] * inv * se1;
        float x2 = acc[mt][2][r] * inv * se2;
        float x3 = acc[mt][3][r] * inv * se3;
        size_t off = (size_t)t * 1024 + hh * 64 + m16;
        dst[off]      = f2bf(x0 * cs.x + x2 * cs.y);
        dst[off + 16] = f2bf(x1);
        dst[off + 32] = f2bf(x2 * cs.x - x0 * cs.y);
        dst[off + 48] = f2bf(x3);
      }
  }
}

// ------------- MFMA flash attention, KEY-SPLIT waves, barrier-free loop ----------
// grid (16 h, 32 y); 256 thr = 4 waves; qt = 31-y (heavy first, 2 blocks/CU).
// Wave w owns keys [kb0+w*32, +32) of each 128-key block and a partial
// Y[64 q][64 d]. Q frags hoisted (loop-invariant); K/V frags are wave-disjoint
// -> loaded DIRECTLY from global (L2-resident; bid%8=h%8 pins head to one XCD);
// no staging, no barriers in the loop. LDS = wave-private P round-trip only.
// 4-way Y/L combine via LDS at the end (2 barriers). no-rescale softmax.
#define PLD 40   // P row stride (u16): 32 keys + 8 pad
#define RPD 20   // combine slice row stride (f32): 16 rows + 4 pad
__global__ __launch_bounds__(256) void attn_flash(const u16* __restrict__ qb,
                                                  const u16* __restrict__ kb,
                                                  const u16* __restrict__ vt,
                                                  u16* __restrict__ yb) {
  // bytes 0..61439: 12 combine slices [64 d][RPD] f32; 61440..62463: Lbuf[4][64].
  // P buffers (4 x [64 q][PLD] u16 = 20480 B) alias the front; barrier-separated.
  __shared__ alignas(16) unsigned char smb[12 * 64 * RPD * 4 + 4 * 64 * 4];
  int h = blockIdx.x;
  int qt = 31 - blockIdx.y;
  int t0 = qt * 64;
  int tid = threadIdx.x;
  int lane = tid & 63, w = tid >> 6;
  int m16 = lane & 15, q = lane >> 4;
  u16* pw = (u16*)smb + w * 64 * PLD;
  // Q B-fragments for all 4 q-tiles, hoisted (32 VGPR, never re-read)
  bf16x8 qa[4][2];
#pragma unroll
  for (int qn = 0; qn < 4; ++qn) {
    const u16* qr = qb + (size_t)(t0 + qn * 16 + m16) * 1024 + h * 64;
    qa[qn][0] = *(const bf16x8*)(qr + q * 8);
    qa[qn][1] = *(const bf16x8*)(qr + 32 + q * 8);
  }
  int wk = w * 32;   // wave's key offset within a 128-key block
  const u16* kbase = kb + (size_t)(wk + m16) * 1024 + h * 64 + q * 8;
  const u16* vbase = vt + (size_t)(h * 64 + m16) * 2048 + wk + q * 8;
  f32x4 Yacc[4][4] = {};                       // [q-tile][d-tile] partial
  float lsum[4] = {0.f, 0.f, 0.f, 0.f};        // per q-tile partial row sums
  int nkb = (qt + 2) >> 1;                     // 128-key blocks (covers qt*64+63)
  bf16x8 kfr[2][2];                            // K A-frags, reg-prefetched
#pragma unroll
  for (int kt = 0; kt < 2; ++kt) {
    kfr[kt][0] = *(const bf16x8*)(kbase + kt * 16384);
    kfr[kt][1] = *(const bf16x8*)(kbase + kt * 16384 + 32);
  }
  for (int kbi = 0; kbi < nkb; ++kbi) {
    int kb0 = kbi * 128;
    // V B-frags for this block (used after QK^T -> latency covered)
    bf16x8 vfr[4];
#pragma unroll
    for (int nt = 0; nt < 4; ++nt)
      vfr[nt] = *(const bf16x8*)(vbase + (size_t)nt * 32768 + kb0);
    // ---- S^T[key][q] = mfma(K, Q): rows = wave's keys, cols = q-rows
    f32x4 ST[2][4] = {};
#pragma unroll
    for (int kt = 0; kt < 2; ++kt)
#pragma unroll
      for (int qn = 0; qn < 4; ++qn) {
        ST[kt][qn] = __builtin_amdgcn_mfma_f32_16x16x32_bf16(kfr[kt][0], qa[qn][0], ST[kt][qn], 0, 0, 0);
        ST[kt][qn] = __builtin_amdgcn_mfma_f32_16x16x32_bf16(kfr[kt][1], qa[qn][1], ST[kt][qn], 0, 0, 0);
      }
    // prefetch next block's K frags
    bf16x8 kn[2][2];
    bool more = (kbi + 1 < nkb);
    if (more) {
      const u16* kp = kbase + (size_t)(kb0 + 128) * 1024;
#pragma unroll
      for (int kt = 0; kt < 2; ++kt) {
        kn[kt][0] = *(const bf16x8*)(kp + kt * 16384);
        kn[kt][1] = *(const bf16x8*)(kp + kt * 16384 + 32);
      }
    }
    // ---- exp + causal mask (only last block touches the diagonal), pack, P->LDS
    bool last = (kbi == nkb - 1);
#pragma unroll
    for (int kt = 0; kt < 2; ++kt) {
      int keyb = kb0 + wk + kt * 16 + q * 4;   // first of this lane's 4 keys
#pragma unroll
      for (int qn = 0; qn < 4; ++qn) {
        int qr_ = t0 + qn * 16 + m16;
        float p0 = __builtin_amdgcn_exp2f(ST[kt][qn][0] * 0.17312340490667562f);
        float p1 = __builtin_amdgcn_exp2f(ST[kt][qn][1] * 0.17312340490667562f);
        float p2 = __builtin_amdgcn_exp2f(ST[kt][qn][2] * 0.17312340490667562f);
        float p3 = __builtin_amdgcn_exp2f(ST[kt][qn][3] * 0.17312340490667562f);
        if (last) {
          p0 = (keyb + 0 <= qr_) ? p0 : 0.f;
          p1 = (keyb + 1 <= qr_) ? p1 : 0.f;
          p2 = (keyb + 2 <= qr_) ? p2 : 0.f;
          p3 = (keyb + 3 <= qr_) ? p3 : 0.f;
        }
        lsum[qn] += (p0 + p1) + (p2 + p3);
        uint2 pk2;
        pk2.x = cvtpk(p0, p1);
        pk2.y = cvtpk(p2, p3);
        *(uint2*)&pw[(qn * 16 + m16) * PLD + kt * 16 + q * 4] = pk2;
      }
    }
    // ---- PV: one K=32 mfma per (q-tile, d-tile) over the wave's 32 keys
    bf16x8 pa[4];
#pragma unroll
    for (int qn = 0; qn < 4; ++qn)
      pa[qn] = *(const bf16x8*)&pw[(qn * 16 + m16) * PLD + q * 8];
#pragma unroll
    for (int qn = 0; qn < 4; ++qn)
#pragma unroll
      for (int nt = 0; nt < 4; ++nt)
        Yacc[qn][nt] = __builtin_amdgcn_mfma_f32_16x16x32_bf16(pa[qn], vfr[nt], Yacc[qn][nt], 0, 0, 0);
    if (more) {
      kfr[0][0] = kn[0][0]; kfr[0][1] = kn[0][1];
      kfr[1][0] = kn[1][0]; kfr[1][1] = kn[1][1];
    }
  }
  // ---- per-wave row sums: reduce over lane-q (cols of same q-row)
#pragma unroll
  for (int qn = 0; qn < 4; ++qn) {
    lsum[qn] += __shfl_xor(lsum[qn], 16);
    lsum[qn] += __shfl_xor(lsum[qn], 32);
  }
  __syncthreads();   // all P use done; combine region may alias P
  float* Yr = (float*)smb;
  float* Lb = (float*)(smb + 12 * 64 * RPD * 4);
  if (q == 0) {
#pragma unroll
    for (int qn = 0; qn < 4; ++qn) Lb[w * 64 + qn * 16 + m16] = lsum[qn];
  }
  // write partial slices qn != w, layout [d col][RPD rows] (f32x4 = 4 rows)
#pragma unroll
  for (int qn = 0; qn < 4; ++qn) {
    if (qn != w) {
      int idx = w * 3 + (qn < w ? qn : qn - 1);
      float* dst = Yr + idx * 64 * RPD;
#pragma unroll
      for (int nt = 0; nt < 4; ++nt)
        *(f32x4*)&dst[(nt * 16 + m16) * RPD + q * 4] = Yacc[qn][nt];
    }
  }
  __syncthreads();
  // wave w combines its own q-tile: own regs + 3 partials, /L, store
  float Lt[4];
#pragma unroll
  for (int r = 0; r < 4; ++r) {
    int row = w * 16 + q * 4 + r;
    Lt[r] = ((Lb[row] + Lb[64 + row]) + (Lb[128 + row] + Lb[192 + row]));
  }
#pragma unroll
  for (int nt = 0; nt < 4; ++nt) {
    f32x4 y = {0.f, 0.f, 0.f, 0.f};
#pragma unroll
    for (int qn = 0; qn < 4; ++qn)
      if (qn == w) y = Yacc[qn][nt];          // static index, runtime select
#pragma unroll
    for (int wp = 0; wp < 4; ++wp) {
      if (wp != w) {
        int idx = wp * 3 + (w < wp ? w : w - 1);
        f32x4 o = *(const f32x4*)&Yr[idx * 64 * RPD + (nt * 16 + m16) * RPD + q * 4];
        y += o;
      }
    }
#pragma unroll
    for (int r = 0; r < 4; ++r) {
      int t = t0 + w * 16 + q * 4 + r;
      yb[(size_t)t * 1024 + h * 64 + nt * 16 + m16] =
          f2bf(y[r] * __builtin_amdgcn_rcpf(Lt[r]));
    }
  }
}

// ------- o-proj GEMM: out[2048][1024] fp32 = yb bf16 @ Wto^T, full K ------
__global__ __launch_bounds__(256) void gemm_o(const u16* __restrict__ A,
                                              const u16* __restrict__ B,
                                              float* __restrict__ C) {
  __shared__ alignas(16) u16 As[128 * GLD];
  __shared__ alignas(16) u16 Bs[64 * GLD];
  int tid = threadIdx.x;
  int bm = blockIdx.y * 128, bn = blockIdx.x * 64;
  int lane = tid & 63, w = tid >> 6;
  int wm = w * 32;
  int m16 = lane & 15, q = lane >> 4;
  f32x4 acc[2][4] = {};
  int srA = tid >> 1, scA = (tid & 1) * 16;
  int srB = tid >> 2, scB = (tid & 3) * 8;
  const u16* aptr = A + (size_t)(bm + srA) * 1024 + scA;
  const u16* bptr = B + (size_t)(bn + srB) * 1024 + scB;
  uint4 a0 = *(const uint4*)(aptr);
  uint4 a1 = *(const uint4*)(aptr + 8);
  uint4 b0 = *(const uint4*)(bptr);
  for (int k0 = 0; k0 < 1024; k0 += 32) {
    __syncthreads();
    *(uint4*)&As[srA * GLD + scA] = a0;
    *(uint4*)&As[srA * GLD + scA + 8] = a1;
    *(uint4*)&Bs[srB * GLD + scB] = b0;
    uint4 na0, na1, nb0;
    if (k0 < 992) {
      na0 = *(const uint4*)(aptr + k0 + 32);
      na1 = *(const uint4*)(aptr + k0 + 40);
      nb0 = *(const uint4*)(bptr + k0 + 32);
    }
    __syncthreads();
    bf16x8 af[2], bfr[4];
#pragma unroll
    for (int mt = 0; mt < 2; ++mt)
      af[mt] = *(const bf16x8*)&As[(wm + mt * 16 + m16) * GLD + q * 8];
#pragma unroll
    for (int nt = 0; nt < 4; ++nt)
      bfr[nt] = *(const bf16x8*)&Bs[(nt * 16 + m16) * GLD + q * 8];
#pragma unroll
    for (int mt = 0; mt < 2; ++mt)
#pragma unroll
      for (int nt = 0; nt < 4; ++nt)
        acc[mt][nt] = __builtin_amdgcn_mfma_f32_16x16x32_bf16(af[mt], bfr[nt], acc[mt][nt], 0, 0, 0);
    if (k0 < 992) { a0 = na0; a1 = na1; b0 = nb0; }
  }
#pragma unroll
  for (int mt = 0; mt < 2; ++mt)
#pragma unroll
    for (int nt = 0; nt < 4; ++nt)
#pragma unroll
      for (int r = 0; r < 4; ++r) {
        int row = bm + wm + mt * 16 + q * 4 + r;
        int col = bn + nt * 16 + m16;
        C[(size_t)row * 1024 + col] = acc[mt][nt][r];
      }
}

extern "C" void kernel_launch(void* const* d_in, const int* in_sizes, int n_in,
                              void* d_out, int out_size, void* d_ws, size_t ws_size,
                              hipStream_t stream) {
  const float* x   = (const float*)d_in[0];
  const float* Wq  = (const float*)d_in[1];
  const float* Wk  = (const float*)d_in[2];
  const float* Wv  = (const float*)d_in[3];
  const float* Wo  = (const float*)d_in[4];
  const float* sqk = (const float*)d_in[5];
  float* out = (float*)d_out;
  char* ws = (char*)d_ws;

  u16*    xb   = (u16*)ws;
  u16*    Wt   = (u16*)(ws + ((size_t)4 << 20));
  float2* rtab = (float2*)(ws + ((size_t)12 << 20));
  u16*    qb16 = (u16*)(ws + ((size_t)16 << 20));
  u16*    kb16 = (u16*)(ws + ((size_t)20 << 20));
  u16*    vt16 = (u16*)(ws + ((size_t)24 << 20));
  u16*    yb   = (u16*)(ws + ((size_t)28 << 20));
  u16*    Wto  = Wt + (size_t)3 * 1024 * 1024;

  prep<<<3072, 256, 0, stream>>>(x, Wq, Wk, Wv, Wo, xb, Wt, rtab);
  gemm_qkv<<<dim3(8, 16, 3), 256, 0, stream>>>(xb, Wt, qb16, kb16, vt16, sqk, rtab);
  attn_flash<<<dim3(16, 32), 256, 0, stream>>>(qb16, kb16, vt16, yb);
  gemm_o<<<dim3(16, 16), 256, 0, stream>>>(yb, Wto, out);
}